// Round 4
// baseline (43793.015 us; speedup 1.0000x reference)
//
#include <hip/hip_runtime.h>
#include <math.h>

#define B_    512
#define T_    512
#define H_    256
#define DIN_  64
#define OL_   8
#define DOUT_ 64

typedef unsigned short u16;
typedef unsigned int u32;
typedef __attribute__((ext_vector_type(8))) short short8;   // 8 bf16 (MFMA A/B frag)
typedef __attribute__((ext_vector_type(4))) float f32x4;    // MFMA C/D frag (16x16)

static __device__ __forceinline__ float sigm(float x){ return 1.0f/(1.0f + expf(-x)); }
static __device__ __forceinline__ float bf2f(u16 h){
  u32 u = ((u32)h) << 16; float f; __builtin_memcpy(&f, &u, 4); return f;
}
static __device__ __forceinline__ u16 f2bf(float f){        // RNE
  u32 u; __builtin_memcpy(&u, &f, 4);
  u = (u + 0x7fffu + ((u >> 16) & 1u)) >> 16;
  return (u16)u;
}
static __device__ __forceinline__ u32 packhl(float f){      // hi<<16 | lo
  u16 h = f2bf(f);
  u16 lo = f2bf(f - bf2f(h));
  return ((u32)h << 16) | (u32)lo;
}

// Grid-wide barrier (all blocks co-resident: grid <= 128 blocks of 256 thr on
// 256 CUs). Device-scope release/acquire per Guideline 16.
static __device__ __forceinline__ void grid_barrier(unsigned* cnt, unsigned target){
  __threadfence();                       // release this thread's global writes
  __syncthreads();
  if (threadIdx.x == 0) {
    __hip_atomic_fetch_add(cnt, 1u, __ATOMIC_RELEASE, __HIP_MEMORY_SCOPE_AGENT);
    while (__hip_atomic_load(cnt, __ATOMIC_ACQUIRE, __HIP_MEMORY_SCOPE_AGENT) < target)
      __builtin_amdgcn_s_sleep(1);
  }
  __syncthreads();
  __threadfence();                       // acquire: invalidate stale cache
}

// ---------------------------------------------------------------------------
// Weight preps
// ---------------------------------------------------------------------------
// WpT[c][d] = sum_e in_W[d][e] * enc_Wih[c][e]   (fold input proj into gates)
__global__ void k_wpt(const float* __restrict__ inW, const float* __restrict__ Wih,
                      float* __restrict__ WpT)
{
  int gid = blockIdx.x * 256 + threadIdx.x;   // 65536
  int c = gid >> 6, d = gid & 63;
  const float* wr = Wih + c * H_;
  const float* ir = inW + d * H_;
  float acc = 0.f;
  #pragma unroll 4
  for (int e = 0; e < H_; e += 4) {
    float4 av = *(const float4*)(ir + e);
    float4 bv = *(const float4*)(wr + e);
    acc += av.x*bv.x + av.y*bv.y + av.z*bv.z + av.w*bv.w;
  }
  WpT[c*64 + d] = acc;
}

// bp[c] = in_b . Wih[c,:] + bih[c] + bhh[c]
__global__ void k_bp(const float* __restrict__ inb, const float* __restrict__ Wih,
                     const float* __restrict__ bih, const float* __restrict__ bhh,
                     float* __restrict__ bp)
{
  int c = blockIdx.x * 256 + threadIdx.x;   // 1024
  const float* wr = Wih + c * H_;
  float acc = bih[c] + bhh[c];
  for (int e = 0; e < H_; ++e) acc += inb[e] * wr[e];
  bp[c] = acc;
}

// permuted bias: n -> (ug,gate,uu): bpp[n] = bp[gate*256 + ug*32 + uu]
__global__ void k_bpp(const float* __restrict__ bp, float* __restrict__ bpp)
{
  int n = blockIdx.x * 256 + threadIdx.x;   // 1024
  int ug = n >> 7, c = n & 127;
  bpp[n] = bp[(c >> 5)*256 + ug*32 + (c & 31)];
}

// dWt[k][j], j<768 covering dec gates i,g,o (f dead: c0=0)
__global__ void k_dwt(const float* __restrict__ dWih, float* __restrict__ dWt)
{
  int gid = blockIdx.x * 256 + threadIdx.x;   // 393216
  int j = gid >> 9, k = gid & 511;
  int row = (j < 256) ? j : (j + 256);
  dWt[k*768 + j] = dWih[row*512 + k];
}

// All 15 MLP weights W[k][n] -> fragment-linear bf16 hi/lo (one launch).
// FL[arr][s][ctg][lane][j] : k = s*32 + (lane>>4)*8 + j, n = ctg*16 + (lane&15)
__global__ void k_wall(const float* __restrict__ wWs, const float* __restrict__ wWl,
                       const float* __restrict__ uWs, const float* __restrict__ uWl,
                       const float* __restrict__ vWs, u16* __restrict__ outb)
{
  int lyr = blockIdx.y;
  const float* W = (lyr < 3)  ? wWs + lyr*65536
                 : (lyr == 3) ? wWl
                 : (lyr < 7)  ? uWs + (lyr-4)*65536
                 : (lyr == 7) ? uWl
                 :              vWs + (lyr-8)*65536;
  u16* out = outb + (size_t)lyr*131072;
  int gid = blockIdx.x * 256 + threadIdx.x;   // 65536
  int k = gid & 255, n = gid >> 8;
  float v = W[k*256 + n];
  int s = k >> 5, j = k & 7;
  int lane = (((k >> 3) & 3) << 4) | (n & 15);
  int fl = ((s*16) + (n >> 4))*512 + lane*8 + j;
  u16 h = f2bf(v);
  out[fl] = h;
  out[65536 + fl] = f2bf(v - bf2f(h));
}

// Whh (1024x256) -> gate-permuted transposed fragment-linear (K=256, N=1024)
__global__ void k_whhfl(const float* __restrict__ Whh, u16* __restrict__ out)
{
  int gid = blockIdx.x * 256 + threadIdx.x;   // 262144
  int j = gid & 7, l = (gid >> 3) & 63, ctg = (gid >> 9) & 63, s = gid >> 15;
  int k = s*32 + (l >> 4)*8 + j;
  int n = ctg*16 + (l & 15);
  int ug = n >> 7, c = n & 127;
  float v = Whh[((c >> 5)*256 + ug*32 + (c & 31))*256 + k];
  int fl = (s*64 + ctg)*512 + l*8 + j;
  u16 h = f2bf(v);
  out[fl] = h;
  out[262144 + fl] = f2bf(v - bf2f(h));
}

// WpT (1024x64) -> gate-permuted fragment-linear (K=64, N=1024)
__global__ void k_wpfl(const float* __restrict__ WpT, u16* __restrict__ out)
{
  int gid = blockIdx.x * 256 + threadIdx.x;   // 65536
  int j = gid & 7, l = (gid >> 3) & 63, ctg = (gid >> 9) & 63, s = gid >> 15;
  int k = s*32 + (l >> 4)*8 + j;              // < 64
  int n = ctg*16 + (l & 15);
  int ug = n >> 7, c = n & 127;
  float v = WpT[((c >> 5)*256 + ug*32 + (c & 31))*64 + k];
  int fl = (s*64 + ctg)*512 + l*8 + j;
  u16 h = f2bf(v);
  out[fl] = h;
  out[65536 + fl] = f2bf(v - bf2f(h));
}

// ---------------------------------------------------------------------------
// Persistent encoder: ALL T steps in one launch. Weights in register B-frags
// loaded ONCE. grid = (CB/32, 8) <= 128 blocks (co-resident), block 256.
// h ping-pong in global + grid barrier per step.
// ---------------------------------------------------------------------------
__global__ __launch_bounds__(256,1) void k_enc_all(
    const float* __restrict__ x, const u16* __restrict__ whhFL,
    const u16* __restrict__ wpFL, const float* __restrict__ bpp,
    u16* __restrict__ hAH, u16* __restrict__ hAL,
    u16* __restrict__ hBH, u16* __restrict__ hBL,
    float* __restrict__ cst, float* __restrict__ enc,
    unsigned* __restrict__ cnt, int nblk)
{
  __shared__ float G[4][32][32];
  const int tid = threadIdx.x, l = tid & 63, w = tid >> 6;
  const int lr = l & 15, lk = l >> 4;
  const int rb = blockIdx.x, ug = blockIdx.y;

  // ---- load persistent B fragments once (Whh: 8 slabs x 2 ct x hi/lo; Wp: 2x2)
  short8 whH[8][2], whL[8][2], wpH[2][2], wpL[2][2];
  #pragma unroll
  for (int s = 0; s < 8; ++s)
    #pragma unroll
    for (int ct = 0; ct < 2; ++ct) {
      int ctg = ug*8 + w*2 + ct;
      whH[s][ct] = *(const short8*)(whhFL + ((size_t)(s*64 + ctg))*512 + l*8);
      whL[s][ct] = *(const short8*)(whhFL + 262144 + ((size_t)(s*64 + ctg))*512 + l*8);
    }
  #pragma unroll
  for (int s = 0; s < 2; ++s)
    #pragma unroll
    for (int ct = 0; ct < 2; ++ct) {
      int ctg = ug*8 + w*2 + ct;
      wpH[s][ct] = *(const short8*)(wpFL + ((size_t)(s*64 + ctg))*512 + l*8);
      wpL[s][ct] = *(const short8*)(wpFL + 65536 + ((size_t)(s*64 + ctg))*512 + l*8);
    }

  for (int t = 0; t < T_; ++t) {
    const u16* hpH = (t & 1) ? hBH : hAH;
    const u16* hpL = (t & 1) ? hBL : hAL;
    u16* hnH      = (t & 1) ? hAH : hBH;
    u16* hnL      = (t & 1) ? hAL : hBL;

    // ---- prefetch x(t) early (latency hidden under h-MFMAs)
    float4 xq[2][4];
    #pragma unroll
    for (int rt = 0; rt < 2; ++rt) {
      int row = rb*32 + rt*16 + lr;
      const float* xr = x + ((size_t)row*T_ + t)*DIN_ + lk*8;
      xq[rt][0] = *(const float4*)(xr);
      xq[rt][1] = *(const float4*)(xr + 4);
      xq[rt][2] = *(const float4*)(xr + 32);
      xq[rt][3] = *(const float4*)(xr + 36);
    }

    f32x4 acc[2][2];
    #pragma unroll
    for (int rt = 0; rt < 2; ++rt)
      #pragma unroll
      for (int ct = 0; ct < 2; ++ct) acc[rt][ct] = (f32x4){0.f,0.f,0.f,0.f};

    // ---- h @ Whh'  (K = 256)
    #pragma unroll
    for (int s = 0; s < 8; ++s) {
      short8 ah[2], al[2];
      #pragma unroll
      for (int rt = 0; rt < 2; ++rt) {
        int row = rb*32 + rt*16 + lr;
        size_t off = (size_t)row*256 + s*32 + lk*8;
        ah[rt] = *(const short8*)(hpH + off);
        al[rt] = *(const short8*)(hpL + off);
      }
      #pragma unroll
      for (int ct = 0; ct < 2; ++ct)
        #pragma unroll
        for (int rt = 0; rt < 2; ++rt) {
          acc[rt][ct] = __builtin_amdgcn_mfma_f32_16x16x32_bf16(ah[rt], whH[s][ct], acc[rt][ct], 0,0,0);
          acc[rt][ct] = __builtin_amdgcn_mfma_f32_16x16x32_bf16(al[rt], whH[s][ct], acc[rt][ct], 0,0,0);
          acc[rt][ct] = __builtin_amdgcn_mfma_f32_16x16x32_bf16(ah[rt], whL[s][ct], acc[rt][ct], 0,0,0);
        }
    }
    // ---- x @ Wp'  (K = 64), split on the fly from prefetched regs
    #pragma unroll
    for (int s = 0; s < 2; ++s) {
      short8 ah[2], al[2];
      #pragma unroll
      for (int rt = 0; rt < 2; ++rt) {
        float4 v0 = xq[rt][s*2], v1 = xq[rt][s*2+1];
        float vv[8] = {v0.x,v0.y,v0.z,v0.w,v1.x,v1.y,v1.z,v1.w};
        #pragma unroll
        for (int j = 0; j < 8; ++j) {
          u16 h = f2bf(vv[j]);
          ah[rt][j] = (short)h;
          al[rt][j] = (short)f2bf(vv[j] - bf2f(h));
        }
      }
      #pragma unroll
      for (int ct = 0; ct < 2; ++ct)
        #pragma unroll
        for (int rt = 0; rt < 2; ++rt) {
          acc[rt][ct] = __builtin_amdgcn_mfma_f32_16x16x32_bf16(ah[rt], wpH[s][ct], acc[rt][ct], 0,0,0);
          acc[rt][ct] = __builtin_amdgcn_mfma_f32_16x16x32_bf16(al[rt], wpH[s][ct], acc[rt][ct], 0,0,0);
          acc[rt][ct] = __builtin_amdgcn_mfma_f32_16x16x32_bf16(ah[rt], wpL[s][ct], acc[rt][ct], 0,0,0);
        }
    }

    // ---- gather gates, activations, c/h update
    #pragma unroll
    for (int rt = 0; rt < 2; ++rt)
      #pragma unroll
      for (int ct = 0; ct < 2; ++ct)
        #pragma unroll
        for (int g = 0; g < 4; ++g)
          G[w][rt*16 + lk*4 + g][ct*16 + lr] = acc[rt][ct][g];
    __syncthreads();

    const int uu = tid & 31, r0 = tid >> 5;
    const int nb = ug*128;
    #pragma unroll
    for (int rr = 0; rr < 4; ++rr) {
      int r = r0 + rr*8;
      float gi = G[0][r][uu] + bpp[nb + uu];
      float gf = G[1][r][uu] + bpp[nb + 32 + uu];
      float gg = G[2][r][uu] + bpp[nb + 64 + uu];
      float go = G[3][r][uu] + bpp[nb + 96 + uu];
      int b = rb*32 + r;
      int unit = ug*32 + uu;
      size_t idx = (size_t)b*256 + unit;
      float cn = sigm(gf)*cst[idx] + sigm(gi)*tanhf(gg);
      float hn = sigm(go)*tanhf(cn);
      cst[idx] = cn;
      u16 hh = f2bf(hn);
      hnH[idx] = hh;
      hnL[idx] = f2bf(hn - bf2f(hh));
      enc[((size_t)b*T_ + t)*256 + unit] = hn;
    }

    if (t < T_ - 1)
      grid_barrier(cnt, (unsigned)(t + 1) * (unsigned)nblk);
  }
}

// ---------------------------------------------------------------------------
// Fused multi-layer MLP (unchanged from r3, verified).
// ---------------------------------------------------------------------------
template<int IN, int FIN>
__global__ __launch_bounds__(512,1) void k_mlp(
    const float* __restrict__ A0, const float* __restrict__ usp,
    const u16* __restrict__ wFL, const float* __restrict__ bs,
    const float* __restrict__ bl, float* __restrict__ Cout,
    float* __restrict__ eout, const float* __restrict__ vWl,
    const float* __restrict__ vbl, int L, int nbs)
{
  extern __shared__ u32 act[];   // [128][256] u32, chunk-swizzled
  const int tid = threadIdx.x, l = tid & 63, w = tid >> 6;
  const int rg = w >> 1, cg = w & 1;
  const int lr = l & 15, lk = l >> 4;
  const int wrow = rg*32;
  const long m0 = (long)blockIdx.x * 128;

  for (int i = tid; i < 8192; i += 512) {        // 128 rows x 64 chunks
    int row = i >> 6, c16 = i & 63;
    long m = m0 + row;
    float4 v = *(const float4*)(A0 + m*256 + c16*4);
    if (IN == 1) {
      const float* ub = usp + (size_t)(m >> 9)*256;
      float4 u4 = *(const float4*)(ub + c16*4);
      v.x = tanhf(v.x + u4.x); v.y = tanhf(v.y + u4.y);
      v.z = tanhf(v.z + u4.z); v.w = tanhf(v.w + u4.w);
    }
    u32* dst = act + row*256 + (c16 ^ (row & 7))*4;
    ((uint4*)dst)[0] = (uint4){packhl(v.x), packhl(v.y), packhl(v.z), packhl(v.w)};
  }

  f32x4 acc[2][8];
  for (int lyr = 0; lyr < L; ++lyr) {
    __syncthreads();
    const u16* wb = wFL + (size_t)lyr*131072;
    #pragma unroll
    for (int rt = 0; rt < 2; ++rt)
      #pragma unroll
      for (int ct = 0; ct < 8; ++ct) acc[rt][ct] = (f32x4){0.f,0.f,0.f,0.f};

    for (int s = 0; s < 8; ++s) {
      short8 ah[2], al[2];
      #pragma unroll
      for (int rt = 0; rt < 2; ++rt) {
        int row = wrow + rt*16 + lr;
        int c16a = s*8 + lk*2;
        int q0 = c16a ^ (row & 7);
        const u32* base = act + row*256;
        uint4 d0 = *(const uint4*)(base + q0*4);
        uint4 d1 = *(const uint4*)(base + (q0 ^ 1)*4);
        u32 q[8] = {d0.x,d0.y,d0.z,d0.w,d1.x,d1.y,d1.z,d1.w};
        #pragma unroll
        for (int j = 0; j < 8; ++j) {
          ah[rt][j] = (short)(q[j] >> 16);
          al[rt][j] = (short)(q[j] & 0xffff);
        }
      }
      #pragma unroll
      for (int ct = 0; ct < 8; ++ct) {
        int ctg = cg*8 + ct;
        const u16* bfp = wb + ((size_t)(s*16 + ctg))*512 + l*8;
        short8 bh = *(const short8*)bfp;
        short8 blo = *(const short8*)(bfp + 65536);
        #pragma unroll
        for (int rt = 0; rt < 2; ++rt) {
          acc[rt][ct] = __builtin_amdgcn_mfma_f32_16x16x32_bf16(ah[rt], bh,  acc[rt][ct], 0,0,0);
          acc[rt][ct] = __builtin_amdgcn_mfma_f32_16x16x32_bf16(al[rt], bh,  acc[rt][ct], 0,0,0);
          acc[rt][ct] = __builtin_amdgcn_mfma_f32_16x16x32_bf16(ah[rt], blo, acc[rt][ct], 0,0,0);
        }
      }
    }
    const float* bptr = (lyr < nbs) ? (bs + lyr*256) : bl;
    const bool dorelu = (lyr < L-1) || (FIN == 1);
    #pragma unroll
    for (int ct = 0; ct < 8; ++ct) {
      float bv = bptr[cg*128 + ct*16 + lr];
      #pragma unroll
      for (int rt = 0; rt < 2; ++rt)
        #pragma unroll
        for (int g = 0; g < 4; ++g) {
          float xv = acc[rt][ct][g] + bv;
          acc[rt][ct][g] = dorelu ? fmaxf(xv, 0.f) : xv;
        }
    }
    if (lyr == L-1) break;
    __syncthreads();
    #pragma unroll
    for (int ct = 0; ct < 8; ++ct) {
      int n = cg*128 + ct*16 + lr;
      #pragma unroll
      for (int rt = 0; rt < 2; ++rt)
        #pragma unroll
        for (int g = 0; g < 4; ++g) {
          int row = wrow + rt*16 + lk*4 + g;
          act[row*256 + (((n >> 2) ^ (row & 7))*4) + (n & 3)] = packhl(acc[rt][ct][g]);
        }
    }
  }

  if (FIN == 0) {
    #pragma unroll
    for (int ct = 0; ct < 8; ++ct) {
      int n = cg*128 + ct*16 + lr;
      #pragma unroll
      for (int rt = 0; rt < 2; ++rt)
        #pragma unroll
        for (int g = 0; g < 4; ++g) {
          long m = m0 + wrow + rt*16 + lk*4 + g;
          Cout[m*256 + n] = acc[rt][ct][g];
        }
    }
  } else {
    float part[2][4];
    #pragma unroll
    for (int rt = 0; rt < 2; ++rt)
      #pragma unroll
      for (int g = 0; g < 4; ++g) part[rt][g] = 0.f;
    #pragma unroll
    for (int ct = 0; ct < 8; ++ct) {
      float vw = vWl[cg*128 + ct*16 + lr];
      #pragma unroll
      for (int rt = 0; rt < 2; ++rt)
        #pragma unroll
        for (int g = 0; g < 4; ++g) part[rt][g] += acc[rt][ct][g] * vw;
    }
    #pragma unroll
    for (int o = 1; o < 16; o <<= 1)
      #pragma unroll
      for (int rt = 0; rt < 2; ++rt)
        #pragma unroll
        for (int g = 0; g < 4; ++g) part[rt][g] += __shfl_xor(part[rt][g], o, 64);
    __syncthreads();
    float* ep = (float*)act;
    if ((l & 15) == 0) {
      #pragma unroll
      for (int rt = 0; rt < 2; ++rt)
        #pragma unroll
        for (int g = 0; g < 4; ++g)
          ep[cg*128 + wrow + rt*16 + lk*4 + g] = part[rt][g];
    }
    __syncthreads();
    for (int r = tid; r < 128; r += 512)
      eout[m0 + r] = ep[r] + ep[128 + r] + vbl[0];
  }
}

// ---------------------------------------------------------------------------
// Fused softmax + context: per batch row, softmax over T then weighted sum.
// ---------------------------------------------------------------------------
__global__ __launch_bounds__(256,2) void k_attn(const float* __restrict__ e,
    const float* __restrict__ enc, float* __restrict__ ct)
{
  __shared__ float as[512];
  __shared__ float red[8];
  const int b = blockIdx.x, tid = threadIdx.x;
  const int lane = tid & 63, w = tid >> 6;
  float v0 = e[b*512 + tid], v1 = e[b*512 + 256 + tid];
  float m = fmaxf(v0, v1);
  #pragma unroll
  for (int o = 32; o; o >>= 1) m = fmaxf(m, __shfl_xor(m, o, 64));
  if (!lane) red[w] = m;
  __syncthreads();
  m = fmaxf(fmaxf(red[0], red[1]), fmaxf(red[2], red[3]));
  float x0 = expf(v0 - m), x1 = expf(v1 - m);
  float sm = x0 + x1;
  #pragma unroll
  for (int o = 32; o; o >>= 1) sm += __shfl_xor(sm, o, 64);
  if (!lane) red[4 + w] = sm;
  __syncthreads();
  float inv = 1.f / (red[4] + red[5] + red[6] + red[7]);
  as[tid] = x0 * inv;
  as[256 + tid] = x1 * inv;
  __syncthreads();
  float acc = 0.f;
  const float* ep = enc + (size_t)b*(T_*H_) + tid;
  #pragma unroll 8
  for (int t = 0; t < 512; ++t) acc += as[t] * ep[t*H_];
  ct[b*H_ + tid] = acc;
}

__global__ __launch_bounds__(256,2) void k_dec_cell(
    const float* __restrict__ ct, float* __restrict__ s, const float* __restrict__ dWt,
    const float* __restrict__ bih, const float* __restrict__ bhh,
    float* __restrict__ dec, int step)
{
  __shared__ float xt[8][516];
  const int tid = threadIdx.x;
  const int b0 = blockIdx.x * 8;
  for (int f = tid; f < 8*128; f += 256) {
    int bb = f >> 7, k4 = f & 127;
    float4 v = (k4 < 64) ? *(const float4*)(ct + (b0+bb)*H_ + k4*4)
                         : *(const float4*)(s  + (b0+bb)*H_ + (k4-64)*4);
    *(float4*)(&xt[bb][k4*4]) = v;
  }
  __syncthreads();
  const int u = tid;
  float ai[8], ag[8], ao[8];
  #pragma unroll
  for (int bb = 0; bb < 8; ++bb) { ai[bb]=0.f; ag[bb]=0.f; ao[bb]=0.f; }
  #pragma unroll 2
  for (int k = 0; k < 512; ++k) {
    float wi = dWt[k*768 + u];
    float wg = dWt[k*768 + 256 + u];
    float wo = dWt[k*768 + 512 + u];
    #pragma unroll
    for (int bb = 0; bb < 8; ++bb) {
      float xv = xt[bb][k];
      ai[bb] += xv*wi; ag[bb] += xv*wg; ao[bb] += xv*wo;
    }
  }
  float bi = bih[u]       + bhh[u];
  float bg = bih[512 + u] + bhh[512 + u];
  float bo = bih[768 + u] + bhh[768 + u];
  #pragma unroll
  for (int bb = 0; bb < 8; ++bb) {
    int b = b0 + bb;
    float cn = sigm(ai[bb] + bi) * tanhf(ag[bb] + bg);
    float hn = sigm(ao[bb] + bo) * tanhf(cn);
    s[b*H_ + u] = hn;
    dec[((size_t)b*OL_ + step)*H_ + u] = hn;
  }
}

__global__ __launch_bounds__(256,2) void k_outproj(
    const float* __restrict__ dec, const float* __restrict__ oW,
    const float* __restrict__ ob, float* __restrict__ out)
{
  const int tid = threadIdx.x;
  const int m0 = blockIdx.x * 16;
  const int d = tid & 63, rr = tid >> 6;
  float bv = ob[d];
  for (int p = 0; p < 4; ++p) {
    int m = m0 + p*4 + rr;
    const float* ar = dec + (size_t)m*H_;
    float acc = bv;
    #pragma unroll 4
    for (int k = 0; k < H_; ++k) acc += ar[k] * oW[k*64 + d];
    out[(size_t)m*64 + d] = acc;
  }
}

// ---------------------------------------------------------------------------
extern "C" void kernel_launch(void* const* d_in, const int* in_sizes, int n_in,
                              void* d_out, int out_size, void* d_ws, size_t ws_size,
                              hipStream_t stream)
{
  (void)in_sizes; (void)n_in;
  const float* x    = (const float*)d_in[0];
  const float* inW  = (const float*)d_in[1];
  const float* inb  = (const float*)d_in[2];
  const float* eWih = (const float*)d_in[3];
  const float* eWhh = (const float*)d_in[4];
  const float* ebih = (const float*)d_in[5];
  const float* ebhh = (const float*)d_in[6];
  const float* dWih = (const float*)d_in[7];
  const float* dbih = (const float*)d_in[9];
  const float* dbhh = (const float*)d_in[10];
  const float* wWs  = (const float*)d_in[11];
  const float* wbs  = (const float*)d_in[12];
  const float* wWl  = (const float*)d_in[13];
  const float* wbl  = (const float*)d_in[14];
  const float* uWs  = (const float*)d_in[15];
  const float* ubs  = (const float*)d_in[16];
  const float* uWl  = (const float*)d_in[17];
  const float* ubl  = (const float*)d_in[18];
  const float* vWs  = (const float*)d_in[19];
  const float* vbs  = (const float*)d_in[20];
  const float* vWl  = (const float*)d_in[21];
  const float* vbl  = (const float*)d_in[22];
  const float* oW   = (const float*)d_in[23];
  const float* ob   = (const float*)d_in[24];
  float* out = (float*)d_out;

  hipFuncSetAttribute((const void*)k_mlp<0,0>, hipFuncAttributeMaxDynamicSharedMemorySize, 131072);
  hipFuncSetAttribute((const void*)k_mlp<1,1>, hipFuncAttributeMaxDynamicSharedMemorySize, 131072);

  const size_t avail = ws_size / 4;
  auto need = [](int cb) -> size_t {
    return 2ull*cb*T_*H_ + (size_t)cb*4096 + 64 + 1800000ull;
  };
  int CB = 512;
  while (CB > 128 && need(CB) > avail) CB >>= 1;
  if (need(CB) > avail) { hipMemsetAsync(d_out, 0, (size_t)out_size*4, stream); return; }

  float* wsf = (float*)d_ws;
  size_t o = 0;
  float* enc = wsf + o;  o += (size_t)CB*T_*H_;
  float* whs = wsf + o;  o += (size_t)CB*T_*H_;
  u16* hAH = (u16*)(wsf + o);             // h planes + cst + sbuf + cnt: one memset
  u16* hAL = hAH + (size_t)CB*256;
  u16* hBH = hAL + (size_t)CB*256;
  u16* hBL = hBH + (size_t)CB*256;        o += (size_t)CB*512;
  float* cst = wsf + o;  o += (size_t)CB*256;
  float* sbuf= wsf + o;  o += (size_t)CB*256;
  unsigned* cnt = (unsigned*)(wsf + o); o += 16;
  float* us  = wsf + o;  o += (size_t)CB*256;
  float* ctx = wsf + o;  o += (size_t)CB*256;
  float* dec = wsf + o;  o += (size_t)CB*2048;
  float* e   = wsf + o;  o += (size_t)CB*512;
  float* WpT = wsf + o;  o += 65536;
  float* bp  = wsf + o;  o += 1024;
  float* bpp = wsf + o;  o += 1024;
  float* dWt = wsf + o;  o += 393216;
  u16* whhFL = (u16*)(wsf + o);  o += 262144;
  u16* wpFL  = (u16*)(wsf + o);  o += 65536;
  u16* mlpFL = (u16*)(wsf + o);

  // ---- weight preps (chunk-invariant)
  k_wpt<<<256, 256, 0, stream>>>(inW, eWih, WpT);
  k_bp <<<4,   256, 0, stream>>>(inb, eWih, ebih, ebhh, bp);
  k_bpp<<<4,   256, 0, stream>>>(bp, bpp);
  k_dwt<<<1536,256, 0, stream>>>(dWih, dWt);
  k_whhfl<<<1024,256,0,stream>>>(eWhh, whhFL);
  k_wpfl <<<256, 256,0,stream>>>(WpT, wpFL);
  k_wall <<<dim3(256,15), 256, 0, stream>>>(wWs, wWl, uWs, uWl, vWs, mlpFL);

  const int gBig = CB * 4;
  const int gU   = CB / 128;
  const int nblk = (CB/32) * 8;

  for (int c0 = 0; c0 < B_; c0 += CB) {
    const float* xc = x + (size_t)c0*T_*DIN_;
    float* outc = out + (size_t)c0*OL_*DOUT_;

    // zero h planes + cst + sbuf + cnt (contiguous)
    hipMemsetAsync(hAH, 0, (size_t)CB*4096 + 64, stream);

    // ---- persistent encoder: all T steps, one launch
    k_enc_all<<<dim3(CB/32, 8), 256, 0, stream>>>(xc, whhFL, wpFL, bpp,
                                                  hAH, hAL, hBH, hBL, cst, enc, cnt, nblk);

    // ---- whs = w_mlp(enc)
    k_mlp<0,0><<<gBig, 512, 131072, stream>>>(enc, nullptr, mlpFL, wbs, wbl,
                                              whs, nullptr, nullptr, nullptr, 4, 3);

    // ---- decode loop
    for (int step = 0; step < OL_; ++step) {
      k_mlp<0,0><<<gU, 512, 131072, stream>>>(sbuf, nullptr, mlpFL + 4ull*131072, ubs, ubl,
                                              us, nullptr, nullptr, nullptr, 4, 3);
      k_mlp<1,1><<<gBig, 512, 131072, stream>>>(whs, us, mlpFL + 8ull*131072, vbs, nullptr,
                                                nullptr, e, vWl, vbl, 7, 7);
      k_attn<<<CB, 256, 0, stream>>>(e, enc, ctx);
      k_dec_cell<<<CB/8, 256, 0, stream>>>(ctx, sbuf, dWt, dbih, dbhh, dec, step);
    }
    k_outproj<<<CB/2, 256, 0, stream>>>(dec, oW, ob, outc);
  }
}